// Round 1
// 319.713 us; speedup vs baseline: 1.0893x; 1.0893x over previous
//
#include <hip/hip_runtime.h>

#define N_NODES 100000
#define N_EDGES 1600000
#define IN_F 256
#define OUT_F 128

#define NBUCK 1563              // ceil(N_NODES / 64) dst-buckets of 64 nodes
#define NCH   250               // chunks over the edge list
#define CH    6400              // edges per chunk = 25*256; NCH*CH == N_EDGES exactly
#define LSUB  8                 // spmm stash depth: bucket capacity 8*256 = 2048
#define LIST_CAP (LSUB * 256)   // mean bucket count 1024, sd 32 -> 2048 is 32 sd

typedef __attribute__((ext_vector_type(8))) short bf16x8;
typedef __attribute__((ext_vector_type(4))) float f32x4;

static __device__ __forceinline__ unsigned f2bf_u(float f) {
    unsigned u = __float_as_uint(f);
    return (u + 0x7FFFu + ((u >> 16) & 1u)) >> 16;      // RNE; inputs finite
}
static __device__ __forceinline__ float bf2f(short s) {
    return __uint_as_float(((unsigned)(unsigned short)s) << 16);
}

// ---------- pass A: per-chunk bucket histogram (LDS atomics only) ----------
__global__ __launch_bounds__(256) void hist_kernel(const int* __restrict__ edge_dst,
                                                   int* __restrict__ hist) {
    __shared__ int h[NBUCK];
    const int t = threadIdx.x;
    for (int b = t; b < NBUCK; b += 256) h[b] = 0;
    __syncthreads();
    const int e0 = blockIdx.x * CH;
    #pragma unroll
    for (int i = 0; i < CH / 256; ++i)
        atomicAdd(&h[edge_dst[e0 + i * 256 + t] >> 6], 1);
    __syncthreads();
    int* o = hist + (size_t)blockIdx.x * NBUCK;          // chunk-major: contiguous write
    for (int b = t; b < NBUCK; b += 256) o[b] = h[b];
}

// ---------- pass B1: per-bucket exclusive scan over chunks (in place) ----------
// thread b walks its column; wave reads/writes 64 consecutive ints per step.
__global__ __launch_bounds__(256) void scan1_kernel(int* __restrict__ hist,
                                                    int* __restrict__ btot) {
    const int b = blockIdx.x * 256 + threadIdx.x;
    if (b >= NBUCK) return;
    int run = 0;
    #pragma unroll 10
    for (int c = 0; c < NCH; ++c) {
        const size_t idx = (size_t)c * NBUCK + b;
        const int v = hist[idx];
        hist[idx] = run;                                  // exclusive within bucket
        run += v;
    }
    btot[b] = run;
}

// ---------- pass B2: single-block exclusive scan of bucket totals ----------
__global__ __launch_bounds__(256) void scan2_kernel(const int* __restrict__ btot,
                                                    int* __restrict__ bstart) {
    __shared__ int wsum[4];
    const int t = threadIdx.x;
    const int lane = t & 63, wave = t >> 6;
    int v[7];
    int s = 0;
    #pragma unroll
    for (int j = 0; j < 7; ++j) {                         // 7*256 = 1792 >= 1563
        const int i = t * 7 + j;
        v[j] = (i < NBUCK) ? btot[i] : 0;
        s += v[j];
    }
    int sc = s;
    #pragma unroll
    for (int off = 1; off < 64; off <<= 1) {
        const int o = __shfl_up(sc, off);
        if (lane >= off) sc += o;
    }
    if (lane == 63) wsum[wave] = sc;
    __syncthreads();
    int add = 0;
    for (int w2 = 0; w2 < wave; ++w2) add += wsum[w2];
    int excl = add + sc - s;
    #pragma unroll
    for (int j = 0; j < 7; ++j) {
        const int i = t * 7 + j;
        if (i < NBUCK) bstart[i] = excl;
        excl += v[j];
    }
    if (t == 255) bstart[NBUCK] = add + sc;               // sentinel = N_EDGES
}

// ---------- pass C: scatter into exact CSR via LDS cursors ----------
// Each chunk's writes to a bucket form a contiguous run (~8 edges = 64B),
// filled within one block's lifetime -> lines written back to HBM once.
__global__ __launch_bounds__(256) void scatter_kernel(const int* __restrict__ edge_src,
                                                      const int* __restrict__ edge_dst,
                                                      const float* __restrict__ edge_weight,
                                                      const int* __restrict__ hist,
                                                      const int* __restrict__ bstart,
                                                      int2* __restrict__ part) {
    __shared__ int cur[NBUCK];
    const int t = threadIdx.x;
    const int c = blockIdx.x;
    const int* hc = hist + (size_t)c * NBUCK;
    for (int b = t; b < NBUCK; b += 256) cur[b] = bstart[b] + hc[b];
    __syncthreads();
    const int e0 = c * CH;
    #pragma unroll
    for (int i = 0; i < CH / 256; ++i) {                  // grid=250 blocks -> ~1/CU;
        const int e = e0 + i * 256 + t;                   // full unroll for MLP depth
        const int d = edge_dst[e];
        const int pos = atomicAdd(&cur[d >> 6], 1);       // LDS atomic, mostly conflict-free
        part[pos] = make_int2(edge_src[e] | ((d & 63) << 24), __float_as_int(edge_weight[e]));
    }
}

// ---------- wt -> bf16 fragment-major: frag(ks,nt), lane(m,q) ----------
// wtf[(ks*8+nt)*512 + lane*8 + j] = bf16(w[(ks*32+q*8+j)*128 + nt*16+m])
__global__ __launch_bounds__(256) void wprep_kernel(const float* __restrict__ w,
                                                    unsigned short* __restrict__ wtf) {
    int id = blockIdx.x * 256 + threadIdx.x;             // 4096 = 64 frags x 64 lanes
    if (id >= 4096) return;
    int f = id >> 6, lane = id & 63;
    int ks = f >> 3, nt = f & 7;
    int m = lane & 15, q = lane >> 4;
    int row = nt * 16 + m;
    int col0 = ks * 32 + q * 8;
    unsigned short* o = wtf + (size_t)f * 512 + lane * 8;
    #pragma unroll
    for (int j = 0; j < 8; ++j)
        o[j] = (unsigned short)f2bf_u(w[(size_t)(col0 + j) * OUT_F + row]);
}

// ---------- MFMA GEMM, LDS-staged x, fragment-major wt ----------
// Block 256 = 4 waves; tile 64 rows. LDS: bf16 x-tile [64][264] = 33.8 KB.
__global__ __launch_bounds__(256) void gemm_mfma_kernel(const float* __restrict__ x,
                                                        const unsigned short* __restrict__ wtf,
                                                        unsigned short* __restrict__ hb) {
    __shared__ unsigned short xs[64][264];               // stride 264: 16B-aligned rows
    const int t = threadIdx.x;
    const int row0 = blockIdx.x * 64;

    // Stage: 64 rows x 256 fp32 -> bf16 LDS, coalesced (4096 float4 / 256 thr).
    const float4* x4 = (const float4*)x;
    #pragma unroll
    for (int i = 0; i < 16; ++i) {
        int idx = t + i * 256;
        int r = idx >> 6, c4 = idx & 63;
        int rg = row0 + r; if (rg >= N_NODES) rg = N_NODES - 1;
        float4 v = x4[(size_t)rg * 64 + c4];
        unsigned u0 = f2bf_u(v.x) | (f2bf_u(v.y) << 16);
        unsigned u1 = f2bf_u(v.z) | (f2bf_u(v.w) << 16);
        *(uint2*)&xs[r][c4 * 4] = make_uint2(u0, u1);
    }
    __syncthreads();

    const int wave = t >> 6, lane = t & 63;
    const int m = lane & 15, quad = lane >> 4;

    // All 8 A-frags up front (ds_read_b128 each).
    bf16x8 af[8];
    #pragma unroll
    for (int ks = 0; ks < 8; ++ks)
        af[ks] = *(const bf16x8*)&xs[wave * 16 + m][ks * 32 + quad * 8];

    f32x4 acc[8];
    #pragma unroll
    for (int nt = 0; nt < 8; ++nt) acc[nt] = (f32x4){0.f, 0.f, 0.f, 0.f};

    const bf16x8* wf = (const bf16x8*)wtf;               // frag-major, coalesced
    #pragma unroll
    for (int ks = 0; ks < 8; ++ks) {
        #pragma unroll
        for (int nt = 0; nt < 8; ++nt) {
            bf16x8 bf = wf[(size_t)(ks * 8 + nt) * 64 + lane];
            acc[nt] = __builtin_amdgcn_mfma_f32_16x16x32_bf16(af[ks], bf, acc[nt], 0, 0, 0);
        }
    }

    const int tile_base = row0 + wave * 16;
    #pragma unroll
    for (int nt = 0; nt < 8; ++nt) {
        #pragma unroll
        for (int r = 0; r < 4; ++r) {
            int orow = tile_base + quad * 4 + r;         // C/D: col=lane&15, row=quad*4+reg
            if (orow < N_NODES)
                hb[(size_t)orow * OUT_F + nt * 16 + m] = (unsigned short)f2bf_u(acc[nt][r]);
        }
    }
}

// ---------- fused SpMM over exact CSR bucket segments ----------
__global__ __launch_bounds__(256) void spmm_kernel(const unsigned short* __restrict__ hb,
                                                   const int* __restrict__ bstart,
                                                   const int2* __restrict__ part,
                                                   const float* __restrict__ b,
                                                   float* __restrict__ out) {
    __shared__ int lh[64];
    __shared__ int lstart[65];
    __shared__ int lcur[64];
    __shared__ int2 list[LIST_CAP];

    const int t = threadIdx.x;
    const int base = blockIdx.x * 64;

    const int s0 = bstart[blockIdx.x];
    int cntb = bstart[blockIdx.x + 1] - s0;
    if (cntb > LIST_CAP) cntb = LIST_CAP;                // statistically unreachable

    if (t < 64) lh[t] = 0;
    __syncthreads();

    // Pass 1: read <=1 edge per (thread, sub) into registers; LDS histogram.
    int2 stash[LSUB];
    int  sn[LSUB];
    #pragma unroll
    for (int sub = 0; sub < LSUB; ++sub) {
        const int idx = sub * 256 + t;
        sn[sub] = -1;
        if (idx < cntb) {
            int2 en = part[(size_t)s0 + idx];
            int n = ((unsigned)en.x) >> 24;
            stash[sub] = make_int2(en.x & 0xFFFFFF, en.y);
            sn[sub] = n;
            atomicAdd(&lh[n], 1);
        }
    }
    __syncthreads();

    // Wave-0 shuffle exclusive scan of the 64 node counters.
    if (t < 64) {
        int v = lh[t];
        int s = v;
        #pragma unroll
        for (int off = 1; off < 64; off <<= 1) {
            int o = __shfl_up(s, off);
            if (t >= off) s += o;
        }
        lstart[t] = s - v;
        lcur[t]   = s - v;
        if (t == 63) lstart[64] = s;
    }
    __syncthreads();

    // Pass 2: scatter stashed edges into per-node LDS lists.
    #pragma unroll
    for (int sub = 0; sub < LSUB; ++sub) {
        if (sn[sub] >= 0) {
            int pos = atomicAdd(&lcur[sn[sub]], 1);
            list[pos] = stash[sub];
        }
    }
    __syncthreads();

    // Gather: 16 lanes per node, 4 node-groups.
    const int j = t & 15;
    const float4* b4 = (const float4*)b;
    const float4 bb0 = b4[j * 2];
    const float4 bb1 = b4[j * 2 + 1];

    #pragma unroll
    for (int g = 0; g < 4; ++g) {
        const int n = g * 16 + (t >> 4);
        const int node = base + n;
        if (node >= N_NODES) continue;
        float4 acc0 = bb0, acc1 = bb1;
        const int p1 = lstart[n + 1];
        for (int p = lstart[n]; p < p1; ++p) {
            const int2 sw = list[p];
            const float wgt = __int_as_float(sw.y);
            const bf16x8 hv = *(const bf16x8*)(hb + (size_t)sw.x * OUT_F + j * 8);
            acc0.x += wgt * bf2f(hv[0]);
            acc0.y += wgt * bf2f(hv[1]);
            acc0.z += wgt * bf2f(hv[2]);
            acc0.w += wgt * bf2f(hv[3]);
            acc1.x += wgt * bf2f(hv[4]);
            acc1.y += wgt * bf2f(hv[5]);
            acc1.z += wgt * bf2f(hv[6]);
            acc1.w += wgt * bf2f(hv[7]);
        }
        float4* o4 = (float4*)(out + (size_t)node * OUT_F + j * 8);
        o4[0] = acc0;
        o4[1] = acc1;
    }
}

extern "C" void kernel_launch(void* const* d_in, const int* in_sizes, int n_in,
                              void* d_out, int out_size, void* d_ws, size_t ws_size,
                              hipStream_t stream) {
    const float* x           = (const float*)d_in[0];
    const int*   edge_src    = (const int*)d_in[1];
    const int*   edge_dst    = (const int*)d_in[2];
    const float* edge_weight = (const float*)d_in[3];
    const float* w           = (const float*)d_in[4];
    const float* b           = (const float*)d_in[5];
    float* out = (float*)d_out;

    // workspace layout (16B-aligned), total ~40 MB
    char* ws = (char*)d_ws;
    size_t off = 0;
    unsigned short* hb  = (unsigned short*)(ws + off);
    off += (size_t)N_NODES * OUT_F * 2;           off = (off + 15) & ~(size_t)15;  // 25.6 MB
    unsigned short* wtf = (unsigned short*)(ws + off);
    off += (size_t)IN_F * OUT_F * 2;              off = (off + 15) & ~(size_t)15;  // 64 KB
    int* hist = (int*)(ws + off);
    off += (size_t)NCH * NBUCK * 4;               off = (off + 15) & ~(size_t)15;  // 1.56 MB
    int* btot = (int*)(ws + off);
    off += (size_t)NBUCK * 4;                     off = (off + 15) & ~(size_t)15;
    int* bstart = (int*)(ws + off);
    off += (size_t)(NBUCK + 1) * 4;               off = (off + 15) & ~(size_t)15;
    int2* part = (int2*)(ws + off);
    off += (size_t)N_EDGES * 8;                                                    // 12.8 MB

    hist_kernel <<<NCH, 256, 0, stream>>>(edge_dst, hist);
    scan1_kernel<<<(NBUCK + 255) / 256, 256, 0, stream>>>(hist, btot);
    scan2_kernel<<<1, 256, 0, stream>>>(btot, bstart);
    scatter_kernel<<<NCH, 256, 0, stream>>>(edge_src, edge_dst, edge_weight, hist, bstart, part);
    wprep_kernel<<<16, 256, 0, stream>>>(w, wtf);
    gemm_mfma_kernel<<<(N_NODES + 63) / 64, 256, 0, stream>>>(x, wtf, hb);
    spmm_kernel<<<NBUCK, 256, 0, stream>>>(hb, bstart, part, b, out);
}